// Round 10
// baseline (110.492 us; speedup 1.0000x reference)
//
#include <hip/hip_runtime.h>
#include <hip/hip_bf16.h>
#include <math.h>

// ---------------------------------------------------------------------------
// MMD loss:  mmd = 2*Sxx_upper/(n(n-1)) + 2*Syy_upper/(m(m-1)) - 2*Sxy/(n*m)
// k(a,b) = exp(-|a-b|^2 / 128)  (sigma^2 = D = 64), N = M = 8192, D = 64.
//
// Algebra: store A' = A * sqrt(log2e)/8 in bf16 and s = 0.5*|a'|^2 (f32).
// Then  exp(-|a-b|^2/128) = exp2( dot(a',b') - s_a - s_b ).
// MFMA C-init = nsx + nsy (register-resident, prologue-loaded).
//
// Hard-won structure lessons (R0..R9):
//  - default __launch_bounds__(256) ONLY. (256,8) -> compiler spills (373us).
//  - NO single-address atomic finalize (~65us serialized tail, R1/R4).
//  - compact balance-ordered grid + prologue-hoisted norms (R6, 79->56us).
//  - B panel in LDS, XOR-swizzle f(x)=x^(((x>>7)&7)<<4) BOTH sides (R7).
//  - R8: occupancy-halving at 16KB LDS was NEUTRAL -> TLP no longer the
//    binder; R9 (512x128 block, 4 A-chunks/stage) got main to 42us with
//    VALUBusy 60%: now ISSUE/ILP-bound, not latency-bound.
//  - R10: runtime `sym` guards inside the loop chop scheduler regions and
//    serialize MFMA->exp per tile. Split at block level: XY path has NO
//    guards (straight-line unrolled chunk, mt0/mt1 + cross-nt overlap);
//    sym path keeps guarded body (needs diagonal masks). VGPR spend on ILP
//    is now a good trade (R8 evidence).
// ---------------------------------------------------------------------------

using short8  = __attribute__((ext_vector_type(8))) short;  // 8 bf16 (4 VGPRs)
using f32x4   = __attribute__((ext_vector_type(4))) float;  // 4 fp32
using float4v = __attribute__((ext_vector_type(4))) float;

#define NROWS 8192
#define DDIM  64
// 1024 XY (dispatched first) + 2*544 sym-upper (512x128 blocks).
#define GRID_MAIN (1024 + 2 * 544)

// sqrt(log2(e)) / 8
#define PRESCALE 0.15014030109830622f

__device__ __forceinline__ float exp2_fast(float x) {
#if __has_builtin(__builtin_amdgcn_exp2f)
    return __builtin_amdgcn_exp2f(x);
#else
    return exp2f(x);
#endif
}

// ---------------------------------------------------------------------------
// Prep: normalize X, prescale, cast X/Y to bf16, compute s = 0.5*|row'|^2
// from the bf16-rounded values. 4 rows per wave, float4 loads. (R6-proven.)
// ---------------------------------------------------------------------------
__global__ __launch_bounds__(256) void mmd_prep(
    const float* __restrict__ z_seq, const float* __restrict__ pmean,
    const float* __restrict__ pstd, const float* __restrict__ z_prior,
    __hip_bfloat16* __restrict__ Xb, __hip_bfloat16* __restrict__ Yb,
    float* __restrict__ sxx, float* __restrict__ syy)
{
    const int tid  = threadIdx.x;
    const int lane = tid & 63;
    const int wid  = tid >> 6;
    const int w    = blockIdx.x * 4 + wid;       // wave id, 0..4095
    const int sub  = lane >> 4;                  // row within wave, 0..3
    const int row  = w * 4 + sub;                // 0..16383
    const int d0   = (lane & 15) * 4;            // dim offset, 0..60

    float4v v;
    __hip_bfloat16* dst;
    float* sdst;
    int r;
    if (row < NROWS) {
        r = row;
        float4v z  = *reinterpret_cast<const float4v*>(z_seq + (size_t)r * DDIM + d0);
        float4v pm = *reinterpret_cast<const float4v*>(pmean + d0);
        float4v ps = *reinterpret_cast<const float4v*>(pstd + d0);
#pragma unroll
        for (int k = 0; k < 4; ++k) v[k] = (z[k] - pm[k]) / ps[k];
        dst = Xb; sdst = sxx;
    } else {
        r = row - NROWS;
        v = *reinterpret_cast<const float4v*>(z_prior + (size_t)r * DDIM + d0);
        dst = Yb; sdst = syy;
    }

    ushort4 hb;
    float sq = 0.0f;
#pragma unroll
    for (int k = 0; k < 4; ++k) {
        __hip_bfloat16 b = __float2bfloat16(v[k] * PRESCALE);
        reinterpret_cast<__hip_bfloat16*>(&hb)[k] = b;
        float vb = __bfloat162float(b);
        sq += vb * vb;
    }
    *reinterpret_cast<ushort4*>(dst + (size_t)r * DDIM + d0) = hb;

    // reduce across the 16 lanes of this row-group (xor<16 stays in group)
#pragma unroll
    for (int off = 8; off; off >>= 1) sq += __shfl_xor(sq, off, 64);
    if ((lane & 15) == 0) sdst[r] = 0.5f * sq;
}

// ---------------------------------------------------------------------------
// Main: compact 1-D grid of ACTIVE blocks only.
// Block tile 512(i) x 128(j): B panel staged once, 4 A-chunks of 128 rows
// swept against it. 4 waves, wave tile 32(i) x 128(j) per chunk.
//   bid <  1024 : XY block, bi = bid>>6 (0..15), bj = bid&63.  GUARD-FREE.
//   bid >= 1024 : t = bid-1024; sym mode = t&1 (0:XX, 1:YY);
//                 u = t>>1 in [0,544): group g=bi has 4 bj's x (g+1) bi's;
//                 bj = 4g+rem/(g+1), bi = rem%(g+1)  (jB >= iB).
// ---------------------------------------------------------------------------
__global__ __launch_bounds__(256) void mmd_main(
    const __hip_bfloat16* __restrict__ Xb, const __hip_bfloat16* __restrict__ Yb,
    const float* __restrict__ sxx, const float* __restrict__ syy,
    double* __restrict__ partials)
{
    __shared__ __align__(16) char Bs[16384];     // 128 cols x 128 B

    const int bid = blockIdx.x;

    int bi, bj;
    bool sym;
    const __hip_bfloat16* A;
    const __hip_bfloat16* Bp;
    const float* sa;
    const float* sb;

    if (bid < 1024) {                       // XY: heavy, uniform, FIRST
        sym = false;
        bi = bid >> 6; bj = bid & 63;
        A = Xb; Bp = Yb; sa = sxx; sb = syy;
    } else {                                // sym upper-triangle blocks
        sym = true;
        const int t = bid - 1024;
        const int u = t >> 1;
        int g = (int)((sqrtf((float)(2 * u + 1)) - 1.0f) * 0.5f);
        while (2 * (g + 1) * (g + 2) <= u) ++g;  // integer fixup of float sqrt
        while (2 * g * (g + 1) > u) --g;
        const int rem = u - 2 * g * (g + 1);     // 0 .. 4(g+1)-1
        const int q   = rem / (g + 1);           // 0..3
        bj = 4 * g + q;
        bi = rem - q * (g + 1);                  // 0..g  (jB >= iB guaranteed)
        if (t & 1) { A = Yb; Bp = Yb; sa = syy; sb = syy; }
        else       { A = Xb; Bp = Xb; sa = sxx; sb = sxx; }
    }

    const int tid  = threadIdx.x;
    const int lane = tid & 63;
    const int wid  = tid >> 6;
    const int quad = lane >> 4;
    const int l15  = lane & 15;

    const int iBlock = bi * 512;
    const int jBlock = bj * 128;

    // ---- Stage B panel -> LDS, source pre-swizzled with f(x)=x^(((x>>7)&7)<<4)
    // so a swizzled read is conflict-free.  16 chunks of 1024B, 4 per wave.
    {
        const char* gB = (const char*)Bp + (size_t)jBlock * 128;
#pragma unroll
        for (int k = 0; k < 4; ++k) {
            const int c  = wid * 4 + k;
            const int x  = c * 1024 + lane * 16;
            const int gx = x ^ (((x >> 7) & 7) << 4);
            __builtin_amdgcn_global_load_lds(
                (const __attribute__((address_space(1))) void*)(gB + gx),
                (__attribute__((address_space(3))) void*)(Bs + c * 1024),
                16, 0, 0);
        }
    }

    // A-chunk 0 wave row origin; chunk c adds c*128.
    int i0 = iBlock + wid * 32;

    short8 af[2][2];
    f32x4  nsx[2];
#pragma unroll
    for (int mt = 0; mt < 2; ++mt) {
        const int ar = i0 + mt * 16 + l15;
#pragma unroll
        for (int ks = 0; ks < 2; ++ks)
            af[mt][ks] = *reinterpret_cast<const short8*>(
                A + (size_t)ar * DDIM + ks * 32 + quad * 8);
        f32x4 s4 = *reinterpret_cast<const f32x4*>(sa + i0 + mt * 16 + quad * 4);
        nsx[mt] = -s4;
    }

    // Hoisted negated column half-norms for this lane's 8 j-tiles.
    float nsy[8];
#pragma unroll
    for (int nt = 0; nt < 8; ++nt) nsy[nt] = -sb[jBlock + l15 + nt * 16];

    __syncthreads();   // staging complete (compiler drains vmcnt first)

    // Per-lane constant swizzle for reads: col&7 == l15&7 (col = 16nt+l15).
    const int swz   = (l15 & 7) << 4;
    const int off0  = (quad * 16) ^ swz;          // ks=0 in-col byte offset
    const int off1  = (quad * 16 + 64) ^ swz;     // ks=1 in-col byte offset
    const char* lb0 = Bs + l15 * 128;

    // 4 accumulators (one per C row) break the serial add chain.
    float ls0 = 0.0f, ls1 = 0.0f, ls2 = 0.0f, ls3 = 0.0f;

    if (!sym) {
        // ---------------- XY path: guard-free straight-line chunks --------
        for (int c = 0; c < 4; ++c) {
#pragma unroll
            for (int nt = 0; nt < 8; ++nt) {
                const char* lp = lb0 + nt * 2048;
                short8 b0 = *reinterpret_cast<const short8*>(lp + off0);
                short8 b1 = *reinterpret_cast<const short8*>(lp + off1);
                const float ny = nsy[nt];
                const f32x4 nyv = {ny, ny, ny, ny};

                f32x4 a0 = nsx[0] + nyv;     // vector add (v_pk_add_f32-able)
                f32x4 a1 = nsx[1] + nyv;
                a0 = __builtin_amdgcn_mfma_f32_16x16x32_bf16(af[0][0], b0, a0, 0, 0, 0);
                a0 = __builtin_amdgcn_mfma_f32_16x16x32_bf16(af[0][1], b1, a0, 0, 0, 0);
                a1 = __builtin_amdgcn_mfma_f32_16x16x32_bf16(af[1][0], b0, a1, 0, 0, 0);
                a1 = __builtin_amdgcn_mfma_f32_16x16x32_bf16(af[1][1], b1, a1, 0, 0, 0);

                ls0 += exp2_fast(a0[0]); ls1 += exp2_fast(a0[1]);
                ls2 += exp2_fast(a0[2]); ls3 += exp2_fast(a0[3]);
                ls0 += exp2_fast(a1[0]); ls1 += exp2_fast(a1[1]);
                ls2 += exp2_fast(a1[2]); ls3 += exp2_fast(a1[3]);
            }

            if (c < 3) {
                const int i0n = i0 + 128;
#pragma unroll
                for (int mt = 0; mt < 2; ++mt) {
                    const int ar = i0n + mt * 16 + l15;
#pragma unroll
                    for (int ks = 0; ks < 2; ++ks)
                        af[mt][ks] = *reinterpret_cast<const short8*>(
                            A + (size_t)ar * DDIM + ks * 32 + quad * 8);
                    f32x4 s4 = *reinterpret_cast<const f32x4*>(sa + i0n + mt * 16 + quad * 4);
                    nsx[mt] = -s4;
                }
                i0 = i0n;
            }
        }
    } else {
        // ---------------- sym path: guarded body (diagonal masks) ---------
        for (int c = 0; c < 4; ++c) {
#pragma unroll
            for (int nt = 0; nt < 8; ++nt) {
                const int jt = jBlock + nt * 16;
                if (jt < i0) continue;       // both mt-tiles below diagonal

                const char* lp = lb0 + nt * 2048;
                short8 b0 = *reinterpret_cast<const short8*>(lp + off0);
                short8 b1 = *reinterpret_cast<const short8*>(lp + off1);

#pragma unroll
                for (int mt = 0; mt < 2; ++mt) {
                    const int it = i0 + mt * 16;
                    if (jt < it) continue;   // tile strictly below diag

                    f32x4 acc4;
#pragma unroll
                    for (int r = 0; r < 4; ++r) acc4[r] = nsx[mt][r] + nsy[nt];
                    acc4 = __builtin_amdgcn_mfma_f32_16x16x32_bf16(af[mt][0], b0, acc4, 0, 0, 0);
                    acc4 = __builtin_amdgcn_mfma_f32_16x16x32_bf16(af[mt][1], b1, acc4, 0, 0, 0);

                    if (jt == it) {
                        // diagonal tile: count only j > i (trace excluded)
                        ls0 += (l15 > quad * 4 + 0) ? exp2_fast(acc4[0]) : 0.0f;
                        ls1 += (l15 > quad * 4 + 1) ? exp2_fast(acc4[1]) : 0.0f;
                        ls2 += (l15 > quad * 4 + 2) ? exp2_fast(acc4[2]) : 0.0f;
                        ls3 += (l15 > quad * 4 + 3) ? exp2_fast(acc4[3]) : 0.0f;
                    } else {
                        ls0 += exp2_fast(acc4[0]);
                        ls1 += exp2_fast(acc4[1]);
                        ls2 += exp2_fast(acc4[2]);
                        ls3 += exp2_fast(acc4[3]);
                    }
                }
            }

            if (c < 3) {
                const int i0n = i0 + 128;
                if (jBlock + 112 < i0n) break;   // all later chunks empty
#pragma unroll
                for (int mt = 0; mt < 2; ++mt) {
                    const int ar = i0n + mt * 16 + l15;
#pragma unroll
                    for (int ks = 0; ks < 2; ++ks)
                        af[mt][ks] = *reinterpret_cast<const short8*>(
                            A + (size_t)ar * DDIM + ks * 32 + quad * 8);
                    f32x4 s4 = *reinterpret_cast<const f32x4*>(sa + i0n + mt * 16 + quad * 4);
                    nsx[mt] = -s4;
                }
                i0 = i0n;
            }
        }
    }

    float lsum = (ls0 + ls1) + (ls2 + ls3);

    // wave reduce
#pragma unroll
    for (int off = 32; off; off >>= 1) lsum += __shfl_xor(lsum, off, 64);

    __shared__ float ws4[4];
    if (lane == 0) ws4[wid] = lsum;
    __syncthreads();
    if (tid == 0) {
        double tot = (double)ws4[0] + (double)ws4[1] + (double)ws4[2] + (double)ws4[3];
        partials[bid] = tot;
    }
}

// ---------------------------------------------------------------------------
// Finalize: reduce GRID_MAIN block partials with per-mode coefficients.
// bid < 1024 -> XY (negative coeff); else sym (x2 folds sum_{i!=j}).
// ---------------------------------------------------------------------------
__global__ __launch_bounds__(256) void mmd_final(
    const double* __restrict__ partials, float* __restrict__ out)
{
    const int tid = threadIdx.x;
    const double cs = 2.0 / (8192.0 * 8191.0);       // sym modes
    const double cx = -2.0 / (8192.0 * 8192.0);      // XY

    double s = 0.0;
    for (int idx = tid; idx < GRID_MAIN; idx += 256) {
        double c = (idx < 1024) ? cx : cs;
        s += partials[idx] * c;
    }
#pragma unroll
    for (int off = 32; off; off >>= 1) s += __shfl_xor(s, off, 64);

    __shared__ double wsum[4];
    const int lane = tid & 63, wid = tid >> 6;
    if (lane == 0) wsum[wid] = s;
    __syncthreads();
    if (tid == 0) {
        double mmd = wsum[0] + wsum[1] + wsum[2] + wsum[3];
        out[0] = (float)(mmd > 0.0 ? mmd : 0.0);
    }
}

// ---------------------------------------------------------------------------
extern "C" void kernel_launch(void* const* d_in, const int* in_sizes, int n_in,
                              void* d_out, int out_size, void* d_ws, size_t ws_size,
                              hipStream_t stream) {
    const float* z_seq   = (const float*)d_in[0];   // [16,512,64]
    const float* pmean   = (const float*)d_in[1];   // [64]
    const float* pstd    = (const float*)d_in[2];   // [64]
    const float* z_prior = (const float*)d_in[3];   // [8192,64]
    float* out = (float*)d_out;

    char* ws = (char*)d_ws;
    __hip_bfloat16* Xb = (__hip_bfloat16*)(ws);                    // 1 MB
    __hip_bfloat16* Yb = (__hip_bfloat16*)(ws + (1u << 20));       // 1 MB
    float* sxx = (float*)(ws + (2u << 20));                        // 32 KB
    float* syy = (float*)(ws + (2u << 20) + 32768);                // 32 KB
    double* partials = (double*)(ws + (2u << 20) + 65536);         // ~17 KB

    mmd_prep<<<dim3(1024), dim3(256), 0, stream>>>(
        z_seq, pmean, pstd, z_prior, Xb, Yb, sxx, syy);
    mmd_main<<<dim3(GRID_MAIN), dim3(256), 0, stream>>>(
        Xb, Yb, sxx, syy, partials);
    mmd_final<<<dim3(1), dim3(256), 0, stream>>>(partials, out);
}

// Round 11
// 104.412 us; speedup vs baseline: 1.0582x; 1.0582x over previous
//
#include <hip/hip_runtime.h>
#include <hip/hip_bf16.h>
#include <math.h>

// ---------------------------------------------------------------------------
// MMD loss:  mmd = 2*Sxx_upper/(n(n-1)) + 2*Syy_upper/(m(m-1)) - 2*Sxy/(n*m)
// k(a,b) = exp(-|a-b|^2 / 128)  (sigma^2 = D = 64), N = M = 8192, D = 64.
//
// Algebra: store A' = A * sqrt(log2e)/8 in bf16 and s = 0.5*|a'|^2 (f32).
// Then  exp(-|a-b|^2/128) = exp2( dot(a',b') - s_a - s_b ).
// MFMA C-operand = nsx (direct, D!=C legal); nsy added post-MFMA in the exp
// argument. No per-tile init movs/adds ahead of the MFMA.
//
// Hard-won structure lessons (R0..R10):
//  - default __launch_bounds__(256) ONLY. (256,8) -> compiler spills (373us).
//  - NO single-address atomic finalize (~65us serialized tail, R1/R4).
//  - Guards ARE the register-pressure governor: any large straight-line BB
//    makes hipcc hoist everything (R1: 108 VGPR; R10: 124 VGPR, both ~2x
//    slower). Keep the runtime-`sym` guarded body.
//  - B panel in LDS, XOR-swizzle f(x)=x^(((x>>7)&7)<<4) BOTH sides (R7).
//  - R8: occupancy-halving at 16KB LDS neutral -> not TLP-bound anymore.
//  - R9 attractor (~42us): ds_read at top of nt body feeds MFMA immediately
//    = ~120cy lgkmcnt stall per nt. R11: named-register 1-deep prefetch
//    rotation (R6's proven pattern, ported from global to LDS), issued
//    unconditionally BEFORE the guard; rotation after. +8 VGPR.
// ---------------------------------------------------------------------------

using short8  = __attribute__((ext_vector_type(8))) short;  // 8 bf16 (4 VGPRs)
using f32x4   = __attribute__((ext_vector_type(4))) float;  // 4 fp32
using float4v = __attribute__((ext_vector_type(4))) float;

#define NROWS 8192
#define DDIM  64
// 1024 XY (dispatched first) + 2*544 sym-upper (512x128 blocks).
#define GRID_MAIN (1024 + 2 * 544)

// sqrt(log2(e)) / 8
#define PRESCALE 0.15014030109830622f

__device__ __forceinline__ float exp2_fast(float x) {
#if __has_builtin(__builtin_amdgcn_exp2f)
    return __builtin_amdgcn_exp2f(x);
#else
    return exp2f(x);
#endif
}

// ---------------------------------------------------------------------------
// Prep: normalize X, prescale, cast X/Y to bf16, compute s = 0.5*|row'|^2
// from the bf16-rounded values. 4 rows per wave, float4 loads. (R6-proven.)
// ---------------------------------------------------------------------------
__global__ __launch_bounds__(256) void mmd_prep(
    const float* __restrict__ z_seq, const float* __restrict__ pmean,
    const float* __restrict__ pstd, const float* __restrict__ z_prior,
    __hip_bfloat16* __restrict__ Xb, __hip_bfloat16* __restrict__ Yb,
    float* __restrict__ sxx, float* __restrict__ syy)
{
    const int tid  = threadIdx.x;
    const int lane = tid & 63;
    const int wid  = tid >> 6;
    const int w    = blockIdx.x * 4 + wid;       // wave id, 0..4095
    const int sub  = lane >> 4;                  // row within wave, 0..3
    const int row  = w * 4 + sub;                // 0..16383
    const int d0   = (lane & 15) * 4;            // dim offset, 0..60

    float4v v;
    __hip_bfloat16* dst;
    float* sdst;
    int r;
    if (row < NROWS) {
        r = row;
        float4v z  = *reinterpret_cast<const float4v*>(z_seq + (size_t)r * DDIM + d0);
        float4v pm = *reinterpret_cast<const float4v*>(pmean + d0);
        float4v ps = *reinterpret_cast<const float4v*>(pstd + d0);
#pragma unroll
        for (int k = 0; k < 4; ++k) v[k] = (z[k] - pm[k]) / ps[k];
        dst = Xb; sdst = sxx;
    } else {
        r = row - NROWS;
        v = *reinterpret_cast<const float4v*>(z_prior + (size_t)r * DDIM + d0);
        dst = Yb; sdst = syy;
    }

    ushort4 hb;
    float sq = 0.0f;
#pragma unroll
    for (int k = 0; k < 4; ++k) {
        __hip_bfloat16 b = __float2bfloat16(v[k] * PRESCALE);
        reinterpret_cast<__hip_bfloat16*>(&hb)[k] = b;
        float vb = __bfloat162float(b);
        sq += vb * vb;
    }
    *reinterpret_cast<ushort4*>(dst + (size_t)r * DDIM + d0) = hb;

    // reduce across the 16 lanes of this row-group (xor<16 stays in group)
#pragma unroll
    for (int off = 8; off; off >>= 1) sq += __shfl_xor(sq, off, 64);
    if ((lane & 15) == 0) sdst[r] = 0.5f * sq;
}

// ---------------------------------------------------------------------------
// Main: compact 1-D grid of ACTIVE blocks only.
// Block tile 512(i) x 128(j): B panel staged once, 4 A-chunks of 128 rows
// swept against it. 4 waves, wave tile 32(i) x 128(j) per chunk.
//   bid <  1024 : XY block, bi = bid>>6 (0..15), bj = bid&63.
//   bid >= 1024 : t = bid-1024; sym mode = t&1 (0:XX, 1:YY);
//                 u = t>>1 in [0,544): group g=bi has 4 bj's x (g+1) bi's;
//                 bj = 4g+rem/(g+1), bi = rem%(g+1)  (jB >= iB).
// ---------------------------------------------------------------------------
__global__ __launch_bounds__(256) void mmd_main(
    const __hip_bfloat16* __restrict__ Xb, const __hip_bfloat16* __restrict__ Yb,
    const float* __restrict__ sxx, const float* __restrict__ syy,
    double* __restrict__ partials)
{
    __shared__ __align__(16) char Bs[16384];     // 128 cols x 128 B

    const int bid = blockIdx.x;

    int bi, bj;
    bool sym;
    const __hip_bfloat16* A;
    const __hip_bfloat16* Bp;
    const float* sa;
    const float* sb;

    if (bid < 1024) {                       // XY: heavy, uniform, FIRST
        sym = false;
        bi = bid >> 6; bj = bid & 63;
        A = Xb; Bp = Yb; sa = sxx; sb = syy;
    } else {                                // sym upper-triangle blocks
        sym = true;
        const int t = bid - 1024;
        const int u = t >> 1;
        int g = (int)((sqrtf((float)(2 * u + 1)) - 1.0f) * 0.5f);
        while (2 * (g + 1) * (g + 2) <= u) ++g;  // integer fixup of float sqrt
        while (2 * g * (g + 1) > u) --g;
        const int rem = u - 2 * g * (g + 1);     // 0 .. 4(g+1)-1
        const int q   = rem / (g + 1);           // 0..3
        bj = 4 * g + q;
        bi = rem - q * (g + 1);                  // 0..g  (jB >= iB guaranteed)
        if (t & 1) { A = Yb; Bp = Yb; sa = syy; sb = syy; }
        else       { A = Xb; Bp = Xb; sa = sxx; sb = sxx; }
    }

    const int tid  = threadIdx.x;
    const int lane = tid & 63;
    const int wid  = tid >> 6;
    const int quad = lane >> 4;
    const int l15  = lane & 15;

    const int iBlock = bi * 512;
    const int jBlock = bj * 128;

    // ---- Stage B panel -> LDS, source pre-swizzled with f(x)=x^(((x>>7)&7)<<4)
    // so a swizzled read is conflict-free.  16 chunks of 1024B, 4 per wave.
    {
        const char* gB = (const char*)Bp + (size_t)jBlock * 128;
#pragma unroll
        for (int k = 0; k < 4; ++k) {
            const int c  = wid * 4 + k;
            const int x  = c * 1024 + lane * 16;
            const int gx = x ^ (((x >> 7) & 7) << 4);
            __builtin_amdgcn_global_load_lds(
                (const __attribute__((address_space(1))) void*)(gB + gx),
                (__attribute__((address_space(3))) void*)(Bs + c * 1024),
                16, 0, 0);
        }
    }

    // A-chunk 0 wave row origin; chunk c adds c*128.
    int i0 = iBlock + wid * 32;

    short8 af[2][2];
    f32x4  nsx[2];
#pragma unroll
    for (int mt = 0; mt < 2; ++mt) {
        const int ar = i0 + mt * 16 + l15;
#pragma unroll
        for (int ks = 0; ks < 2; ++ks)
            af[mt][ks] = *reinterpret_cast<const short8*>(
                A + (size_t)ar * DDIM + ks * 32 + quad * 8);
        f32x4 s4 = *reinterpret_cast<const f32x4*>(sa + i0 + mt * 16 + quad * 4);
        nsx[mt] = -s4;
    }

    // Hoisted negated column half-norms for this lane's 8 j-tiles.
    float nsy[8];
#pragma unroll
    for (int nt = 0; nt < 8; ++nt) nsy[nt] = -sb[jBlock + l15 + nt * 16];

    __syncthreads();   // staging complete (compiler drains vmcnt first)

    // Per-lane constant swizzle for reads: col&7 == l15&7 (col = 16nt+l15).
    const int swz   = (l15 & 7) << 4;
    const int off0  = (quad * 16) ^ swz;          // ks=0 in-col byte offset
    const int off1  = (quad * 16 + 64) ^ swz;     // ks=1 in-col byte offset
    const char* lb0 = Bs + l15 * 128;

    // 4 accumulators (one per C row) break the serial add chain.
    float ls0 = 0.0f, ls1 = 0.0f, ls2 = 0.0f, ls3 = 0.0f;

    // B-fragment rotation: b0/b1 hold slot nt; pb0/pb1 prefetch (nt+1)&7.
    // (Panel identical across chunks, so wrap-around prefetch is correct.)
    short8 b0 = *reinterpret_cast<const short8*>(lb0 + off0);
    short8 b1 = *reinterpret_cast<const short8*>(lb0 + off1);

    for (int c = 0; c < 4; ++c) {
#pragma unroll
        for (int nt = 0; nt < 8; ++nt) {
            // Unconditional prefetch of the next slot, issued BEFORE the
            // guard so its ~120cy LDS latency hides under this nt's work.
            const char* lpn = lb0 + (((nt + 1) & 7) * 2048);
            short8 pb0 = *reinterpret_cast<const short8*>(lpn + off0);
            short8 pb1 = *reinterpret_cast<const short8*>(lpn + off1);

            const int jt = jBlock + nt * 16;
            if (!(sym && jt < i0)) {
#pragma unroll
                for (int mt = 0; mt < 2; ++mt) {
                    const int it = i0 + mt * 16;
                    if (sym && jt < it) continue;   // tile strictly below diag

                    // C-operand = nsx directly (no init adds/movs).
                    f32x4 acc4 = __builtin_amdgcn_mfma_f32_16x16x32_bf16(
                        af[mt][0], b0, nsx[mt], 0, 0, 0);
                    acc4 = __builtin_amdgcn_mfma_f32_16x16x32_bf16(
                        af[mt][1], b1, acc4, 0, 0, 0);
                    const float ny = nsy[nt];

                    if (sym && jt == it) {
                        // diagonal tile: count only j > i (trace excluded)
                        ls0 += (l15 > quad * 4 + 0) ? exp2_fast(acc4[0] + ny) : 0.0f;
                        ls1 += (l15 > quad * 4 + 1) ? exp2_fast(acc4[1] + ny) : 0.0f;
                        ls2 += (l15 > quad * 4 + 2) ? exp2_fast(acc4[2] + ny) : 0.0f;
                        ls3 += (l15 > quad * 4 + 3) ? exp2_fast(acc4[3] + ny) : 0.0f;
                    } else {
                        ls0 += exp2_fast(acc4[0] + ny);
                        ls1 += exp2_fast(acc4[1] + ny);
                        ls2 += exp2_fast(acc4[2] + ny);
                        ls3 += exp2_fast(acc4[3] + ny);
                    }
                }
            }

            b0 = pb0; b1 = pb1;   // rotate (named regs, no dynamic indexing)
        }

        // Load next chunk's A fragments; latency hides under loop-around.
        if (c < 3) {
            const int i0n = i0 + 128;
            if (sym && jBlock + 112 < i0n) break;   // all later chunks empty
#pragma unroll
            for (int mt = 0; mt < 2; ++mt) {
                const int ar = i0n + mt * 16 + l15;
#pragma unroll
                for (int ks = 0; ks < 2; ++ks)
                    af[mt][ks] = *reinterpret_cast<const short8*>(
                        A + (size_t)ar * DDIM + ks * 32 + quad * 8);
                f32x4 s4 = *reinterpret_cast<const f32x4*>(sa + i0n + mt * 16 + quad * 4);
                nsx[mt] = -s4;
            }
            i0 = i0n;
        }
    }

    float lsum = (ls0 + ls1) + (ls2 + ls3);

    // wave reduce
#pragma unroll
    for (int off = 32; off; off >>= 1) lsum += __shfl_xor(lsum, off, 64);

    __shared__ float ws4[4];
    if (lane == 0) ws4[wid] = lsum;
    __syncthreads();
    if (tid == 0) {
        double tot = (double)ws4[0] + (double)ws4[1] + (double)ws4[2] + (double)ws4[3];
        partials[bid] = tot;
    }
}

// ---------------------------------------------------------------------------
// Finalize: reduce GRID_MAIN block partials with per-mode coefficients.
// bid < 1024 -> XY (negative coeff); else sym (x2 folds sum_{i!=j}).
// ---------------------------------------------------------------------------
__global__ __launch_bounds__(256) void mmd_final(
    const double* __restrict__ partials, float* __restrict__ out)
{
    const int tid = threadIdx.x;
    const double cs = 2.0 / (8192.0 * 8191.0);       // sym modes
    const double cx = -2.0 / (8192.0 * 8192.0);      // XY

    double s = 0.0;
    for (int idx = tid; idx < GRID_MAIN; idx += 256) {
        double c = (idx < 1024) ? cx : cs;
        s += partials[idx] * c;
    }
#pragma unroll
    for (int off = 32; off; off >>= 1) s += __shfl_xor(s, off, 64);

    __shared__ double wsum[4];
    const int lane = tid & 63, wid = tid >> 6;
    if (lane == 0) wsum[wid] = s;
    __syncthreads();
    if (tid == 0) {
        double mmd = wsum[0] + wsum[1] + wsum[2] + wsum[3];
        out[0] = (float)(mmd > 0.0 ? mmd : 0.0);
    }
}

// ---------------------------------------------------------------------------
extern "C" void kernel_launch(void* const* d_in, const int* in_sizes, int n_in,
                              void* d_out, int out_size, void* d_ws, size_t ws_size,
                              hipStream_t stream) {
    const float* z_seq   = (const float*)d_in[0];   // [16,512,64]
    const float* pmean   = (const float*)d_in[1];   // [64]
    const float* pstd    = (const float*)d_in[2];   // [64]
    const float* z_prior = (const float*)d_in[3];   // [8192,64]
    float* out = (float*)d_out;

    char* ws = (char*)d_ws;
    __hip_bfloat16* Xb = (__hip_bfloat16*)(ws);                    // 1 MB
    __hip_bfloat16* Yb = (__hip_bfloat16*)(ws + (1u << 20));       // 1 MB
    float* sxx = (float*)(ws + (2u << 20));                        // 32 KB
    float* syy = (float*)(ws + (2u << 20) + 32768);                // 32 KB
    double* partials = (double*)(ws + (2u << 20) + 65536);         // ~17 KB

    mmd_prep<<<dim3(1024), dim3(256), 0, stream>>>(
        z_seq, pmean, pstd, z_prior, Xb, Yb, sxx, syy);
    mmd_main<<<dim3(GRID_MAIN), dim3(256), 0, stream>>>(
        Xb, Yb, sxx, syy, partials);
    mmd_final<<<dim3(1), dim3(256), 0, stream>>>(partials, out);
}

// Round 12
// 95.789 us; speedup vs baseline: 1.1535x; 1.0900x over previous
//
#include <hip/hip_runtime.h>
#include <hip/hip_bf16.h>
#include <math.h>

// ---------------------------------------------------------------------------
// MMD loss:  mmd = 2*Sxx_upper/(n(n-1)) + 2*Syy_upper/(m(m-1)) - 2*Sxy/(n*m)
// k(a,b) = exp(-|a-b|^2 / 128)  (sigma^2 = D = 64), N = M = 8192, D = 64.
//
// Algebra: store A' = A * sqrt(log2e)/8 in bf16 and ns = -0.5*|a'|^2 (f32,
// NEGATED in prep). Then k = exp2( dot(a',b') + ns_a + ns_b )
//                         = exp2( dot + ns_a ) * exp2( ns_b ).
// MFMA C-operand = ns_a (16 regs, C/D row order); ey = exp2(ns_b) once per
// 32x32 tile; per element just exp2 + fma.
//
// Hard-won structure lessons (R0..R11):
//  - default __launch_bounds__(256) ONLY. (256,8) -> compiler spills (373us).
//  - NO single-address atomic finalize (~65us serialized tail, R1/R4).
//  - Guards ARE the register-pressure governor (R1: 108 VGPR, R10: 124).
//  - B panel in LDS, XOR-swizzle f(x)=x^(((x>>7)&7)<<4) BOTH sides (R7).
//  - TLP beyond ~3 waves/SIMD is neutral (R8); 1-deep ds prefetch neutral-
//    to-negative via VGPR cliff at 64 (R11).
//  - Plateau 41-45us across 6 variants with no pipe >25% => cost follows
//    per-tile instruction count + MFMA->VALU epilogue transitions.
//  - R12: 32x32x16 MFMA (half the MFMA/loop instr per element, 4x fewer
//    MFMA-result-read events) + multiplicative ey fold (kills per-element
//    norm adds). C/D layout HW-verified (m74/m101); A/B = same k-slice
//    pattern as our proven 16x16x32 usage.
// ---------------------------------------------------------------------------

using short8  = __attribute__((ext_vector_type(8))) short;   // 8 bf16
using f32x4   = __attribute__((ext_vector_type(4))) float;
using f32x16  = __attribute__((ext_vector_type(16))) float;
using float4v = __attribute__((ext_vector_type(4))) float;

#define NROWS 8192
#define DDIM  64
// 1024 XY (dispatched first) + 2*544 sym-upper (512x128 blocks).
#define GRID_MAIN (1024 + 2 * 544)

// sqrt(log2(e)) / 8
#define PRESCALE 0.15014030109830622f

__device__ __forceinline__ float exp2_fast(float x) {
#if __has_builtin(__builtin_amdgcn_exp2f)
    return __builtin_amdgcn_exp2f(x);
#else
    return exp2f(x);
#endif
}

// ---------------------------------------------------------------------------
// Prep: normalize X, prescale, cast X/Y to bf16, compute ns = -0.5*|row'|^2
// (NEGATED: used directly as MFMA C-init / exp2 argument in main).
// 4 rows per wave, float4 loads. (R6-proven.)
// ---------------------------------------------------------------------------
__global__ __launch_bounds__(256) void mmd_prep(
    const float* __restrict__ z_seq, const float* __restrict__ pmean,
    const float* __restrict__ pstd, const float* __restrict__ z_prior,
    __hip_bfloat16* __restrict__ Xb, __hip_bfloat16* __restrict__ Yb,
    float* __restrict__ sxx, float* __restrict__ syy)
{
    const int tid  = threadIdx.x;
    const int lane = tid & 63;
    const int wid  = tid >> 6;
    const int w    = blockIdx.x * 4 + wid;       // wave id, 0..4095
    const int sub  = lane >> 4;                  // row within wave, 0..3
    const int row  = w * 4 + sub;                // 0..16383
    const int d0   = (lane & 15) * 4;            // dim offset, 0..60

    float4v v;
    __hip_bfloat16* dst;
    float* sdst;
    int r;
    if (row < NROWS) {
        r = row;
        float4v z  = *reinterpret_cast<const float4v*>(z_seq + (size_t)r * DDIM + d0);
        float4v pm = *reinterpret_cast<const float4v*>(pmean + d0);
        float4v ps = *reinterpret_cast<const float4v*>(pstd + d0);
#pragma unroll
        for (int k = 0; k < 4; ++k) v[k] = (z[k] - pm[k]) / ps[k];
        dst = Xb; sdst = sxx;
    } else {
        r = row - NROWS;
        v = *reinterpret_cast<const float4v*>(z_prior + (size_t)r * DDIM + d0);
        dst = Yb; sdst = syy;
    }

    ushort4 hb;
    float sq = 0.0f;
#pragma unroll
    for (int k = 0; k < 4; ++k) {
        __hip_bfloat16 b = __float2bfloat16(v[k] * PRESCALE);
        reinterpret_cast<__hip_bfloat16*>(&hb)[k] = b;
        float vb = __bfloat162float(b);
        sq += vb * vb;
    }
    *reinterpret_cast<ushort4*>(dst + (size_t)r * DDIM + d0) = hb;

    // reduce across the 16 lanes of this row-group (xor<16 stays in group)
#pragma unroll
    for (int off = 8; off; off >>= 1) sq += __shfl_xor(sq, off, 64);
    if ((lane & 15) == 0) sdst[r] = -0.5f * sq;   // NEGATED
}

// ---------------------------------------------------------------------------
// Main: compact 1-D grid of ACTIVE blocks only.
// Block tile 512(i) x 128(j): B panel staged once, 4 A-chunks of 128 rows.
// 4 waves; wave tile 32(i) x 128(j) per chunk as 4 j-subtiles of 32x32,
// computed with v_mfma_f32_32x32x16_bf16 (K=16 x4 chained = K64).
//   bid <  1024 : XY block, bi = bid>>6 (0..15), bj = bid&63.
//   bid >= 1024 : t = bid-1024; sym mode = t&1 (0:XX, 1:YY);
//                 u = t>>1 in [0,544): bj = 4g+rem/(g+1), bi = rem%(g+1).
// 32x32 C/D layout: col = lane&31, row = (reg&3) + 8*(reg>>2) + 4*(lane>>5).
// A/B operand: row/col = lane&31, k = 8*(lane>>5) + elem(0..7).
// ---------------------------------------------------------------------------
__global__ __launch_bounds__(256) void mmd_main(
    const __hip_bfloat16* __restrict__ Xb, const __hip_bfloat16* __restrict__ Yb,
    const float* __restrict__ sxx, const float* __restrict__ syy,
    double* __restrict__ partials)
{
    __shared__ __align__(16) char Bs[16384];     // 128 cols x 128 B

    const int bid = blockIdx.x;

    int bi, bj;
    bool sym;
    const __hip_bfloat16* A;
    const __hip_bfloat16* Bp;
    const float* sa;
    const float* sb;

    if (bid < 1024) {                       // XY: heavy, uniform, FIRST
        sym = false;
        bi = bid >> 6; bj = bid & 63;
        A = Xb; Bp = Yb; sa = sxx; sb = syy;
    } else {                                // sym upper-triangle blocks
        sym = true;
        const int t = bid - 1024;
        const int u = t >> 1;
        int g = (int)((sqrtf((float)(2 * u + 1)) - 1.0f) * 0.5f);
        while (2 * (g + 1) * (g + 2) <= u) ++g;  // integer fixup of float sqrt
        while (2 * g * (g + 1) > u) --g;
        const int rem = u - 2 * g * (g + 1);     // 0 .. 4(g+1)-1
        const int q   = rem / (g + 1);           // 0..3
        bj = 4 * g + q;
        bi = rem - q * (g + 1);                  // 0..g  (jB >= iB guaranteed)
        if (t & 1) { A = Yb; Bp = Yb; sa = syy; sb = syy; }
        else       { A = Xb; Bp = Xb; sa = sxx; sb = sxx; }
    }

    const int tid  = threadIdx.x;
    const int lane = tid & 63;
    const int wid  = tid >> 6;
    const int l31  = lane & 31;
    const int h    = lane >> 5;                  // 0/1: k-half

    const int iBlock = bi * 512;
    const int jBlock = bj * 128;

    // ---- Stage B panel -> LDS, source pre-swizzled with f(x)=x^(((x>>7)&7)<<4)
    // so a swizzled read is conflict-free.  16 chunks of 1024B, 4 per wave.
    {
        const char* gB = (const char*)Bp + (size_t)jBlock * 128;
#pragma unroll
        for (int k = 0; k < 4; ++k) {
            const int c  = wid * 4 + k;
            const int x  = c * 1024 + lane * 16;
            const int gx = x ^ (((x >> 7) & 7) << 4);
            __builtin_amdgcn_global_load_lds(
                (const __attribute__((address_space(1))) void*)(gB + gx),
                (__attribute__((address_space(3))) void*)(Bs + c * 1024),
                16, 0, 0);
        }
    }

    // A-chunk 0 wave row origin; chunk c adds 128.
    int i0 = iBlock + wid * 32;

    // A fragments (4 k-slices) + C-init (negated row half-norms in C/D
    // register order: reg r <- rows 8*(r>>2) + 4h + (r&3)).
    short8 af0, af1, af2, af3;
    f32x16 cin;
    {
        const char* arow = (const char*)A + (size_t)(i0 + l31) * 128 + 16 * h;
        af0 = *reinterpret_cast<const short8*>(arow);
        af1 = *reinterpret_cast<const short8*>(arow + 32);
        af2 = *reinterpret_cast<const short8*>(arow + 64);
        af3 = *reinterpret_cast<const short8*>(arow + 96);
        const float* sna = sa + i0 + 4 * h;
#pragma unroll
        for (int q = 0; q < 4; ++q) {
            f32x4 t = *reinterpret_cast<const f32x4*>(sna + 8 * q);
            cin[4 * q + 0] = t[0]; cin[4 * q + 1] = t[1];
            cin[4 * q + 2] = t[2]; cin[4 * q + 3] = t[3];
        }
    }

    // Negated column half-norms for this lane's 4 j-subtiles.
    float nsy4[4];
#pragma unroll
    for (int nt = 0; nt < 4; ++nt) nsy4[nt] = sb[jBlock + nt * 32 + l31];

    __syncthreads();   // staging complete (compiler drains vmcnt first)

    // Per-lane constant swizzle for reads: col&7 == l31&7 (col = 32nt+l31).
    const int swz = (l31 & 7) << 4;
    const int bo0 = (16 * h +  0) ^ swz;
    const int bo1 = (16 * h + 32) ^ swz;
    const int bo2 = (16 * h + 64) ^ swz;
    const int bo3 = (16 * h + 96) ^ swz;
    const char* lbbase = Bs + l31 * 128;

    // 4 accumulators break the serial add chain.
    float ls0 = 0.0f, ls1 = 0.0f, ls2 = 0.0f, ls3 = 0.0f;

    for (int c = 0; c < 4; ++c) {
#pragma unroll
        for (int nt = 0; nt < 4; ++nt) {
            const int jt = jBlock + nt * 32;
            if (sym && jt < i0) continue;        // tile strictly below diag

            const char* lp = lbbase + nt * 4096;
            short8 b0 = *reinterpret_cast<const short8*>(lp + bo0);
            short8 b1 = *reinterpret_cast<const short8*>(lp + bo1);
            short8 b2 = *reinterpret_cast<const short8*>(lp + bo2);
            short8 b3 = *reinterpret_cast<const short8*>(lp + bo3);

            f32x16 acc = __builtin_amdgcn_mfma_f32_32x32x16_bf16(af0, b0, cin, 0, 0, 0);
            acc = __builtin_amdgcn_mfma_f32_32x32x16_bf16(af1, b1, acc, 0, 0, 0);
            acc = __builtin_amdgcn_mfma_f32_32x32x16_bf16(af2, b2, acc, 0, 0, 0);
            acc = __builtin_amdgcn_mfma_f32_32x32x16_bf16(af3, b3, acc, 0, 0, 0);

            const float ey = exp2_fast(nsy4[nt]);   // exp2(-s_b), once/tile

            if (sym && jt == i0) {
                // diagonal tile: count only j > i; row_r = (r&3)+8*(r>>2)+4h
                const int rb = 4 * h;
#pragma unroll
                for (int r = 0; r < 16; ++r) {
                    const int rowr = rb + (r & 3) + 8 * (r >> 2);
                    float v = exp2_fast(acc[r]) * ey;
                    float m = (l31 > rowr) ? v : 0.0f;
                    if ((r & 3) == 0) ls0 += m;
                    else if ((r & 3) == 1) ls1 += m;
                    else if ((r & 3) == 2) ls2 += m;
                    else ls3 += m;
                }
            } else {
#pragma unroll
                for (int r = 0; r < 16; ++r) {
                    float e = exp2_fast(acc[r]);
                    if ((r & 3) == 0) ls0 = fmaf(e, ey, ls0);
                    else if ((r & 3) == 1) ls1 = fmaf(e, ey, ls1);
                    else if ((r & 3) == 2) ls2 = fmaf(e, ey, ls2);
                    else ls3 = fmaf(e, ey, ls3);
                }
            }
        }

        // Load next chunk's A fragments + C-init.
        if (c < 3) {
            const int i0n = i0 + 128;
            if (sym && jBlock + 96 < i0n) break;    // all later tiles empty
            const char* arow = (const char*)A + (size_t)(i0n + l31) * 128 + 16 * h;
            af0 = *reinterpret_cast<const short8*>(arow);
            af1 = *reinterpret_cast<const short8*>(arow + 32);
            af2 = *reinterpret_cast<const short8*>(arow + 64);
            af3 = *reinterpret_cast<const short8*>(arow + 96);
            const float* sna = sa + i0n + 4 * h;
#pragma unroll
            for (int q = 0; q < 4; ++q) {
                f32x4 t = *reinterpret_cast<const f32x4*>(sna + 8 * q);
                cin[4 * q + 0] = t[0]; cin[4 * q + 1] = t[1];
                cin[4 * q + 2] = t[2]; cin[4 * q + 3] = t[3];
            }
            i0 = i0n;
        }
    }

    float lsum = (ls0 + ls1) + (ls2 + ls3);

    // wave reduce
#pragma unroll
    for (int off = 32; off; off >>= 1) lsum += __shfl_xor(lsum, off, 64);

    __shared__ float ws4[4];
    if (lane == 0) ws4[wid] = lsum;
    __syncthreads();
    if (tid == 0) {
        double tot = (double)ws4[0] + (double)ws4[1] + (double)ws4[2] + (double)ws4[3];
        partials[bid] = tot;
    }
}

// ---------------------------------------------------------------------------
// Finalize: reduce GRID_MAIN block partials with per-mode coefficients.
// bid < 1024 -> XY (negative coeff); else sym (x2 folds sum_{i!=j}).
// ---------------------------------------------------------------------------
__global__ __launch_bounds__(256) void mmd_final(
    const double* __restrict__ partials, float* __restrict__ out)
{
    const int tid = threadIdx.x;
    const double cs = 2.0 / (8192.0 * 8191.0);       // sym modes
    const double cx = -2.0 / (8192.0 * 8192.0);      // XY

    double s = 0.0;
    for (int idx = tid; idx < GRID_MAIN; idx += 256) {
        double c = (idx < 1024) ? cx : cs;
        s += partials[idx] * c;
    }
#pragma unroll
    for (int off = 32; off; off >>= 1) s += __shfl_xor(s, off, 64);

    __shared__ double wsum[4];
    const int lane = tid & 63, wid = tid >> 6;
    if (lane == 0) wsum[wid] = s;
    __syncthreads();
    if (tid == 0) {
        double mmd = wsum[0] + wsum[1] + wsum[2] + wsum[3];
        out[0] = (float)(mmd > 0.0 ? mmd : 0.0);
    }
}

// ---------------------------------------------------------------------------
extern "C" void kernel_launch(void* const* d_in, const int* in_sizes, int n_in,
                              void* d_out, int out_size, void* d_ws, size_t ws_size,
                              hipStream_t stream) {
    const float* z_seq   = (const float*)d_in[0];   // [16,512,64]
    const float* pmean   = (const float*)d_in[1];   // [64]
    const float* pstd    = (const float*)d_in[2];   // [64]
    const float* z_prior = (const float*)d_in[3];   // [8192,64]
    float* out = (float*)d_out;

    char* ws = (char*)d_ws;
    __hip_bfloat16* Xb = (__hip_bfloat16*)(ws);                    // 1 MB
    __hip_bfloat16* Yb = (__hip_bfloat16*)(ws + (1u << 20));       // 1 MB
    float* sxx = (float*)(ws + (2u << 20));                        // 32 KB
    float* syy = (float*)(ws + (2u << 20) + 32768);                // 32 KB
    double* partials = (double*)(ws + (2u << 20) + 65536);         // ~17 KB

    mmd_prep<<<dim3(1024), dim3(256), 0, stream>>>(
        z_seq, pmean, pstd, z_prior, Xb, Yb, sxx, syy);
    mmd_main<<<dim3(GRID_MAIN), dim3(256), 0, stream>>>(
        Xb, Yb, sxx, syy, partials);
    mmd_final<<<dim3(1), dim3(256), 0, stream>>>(partials, out);
}